// Round 14
// baseline (140.790 us; speedup 1.0000x reference)
//
#include <hip/hip_runtime.h>

namespace {

typedef short    v4s __attribute__((ext_vector_type(4)));
typedef float    v4f __attribute__((ext_vector_type(4)));
typedef float    f4  __attribute__((ext_vector_type(4)));
typedef unsigned u2  __attribute__((ext_vector_type(2)));

constexpr int Tt = 512;
constexpr int Dd = 64;
constexpr float LN2 = 0.69314718055994530942f;

// RNE bf16 pack (bit-twiddle; off critical path)
__device__ __forceinline__ unsigned pk_bf16(float a, float b) {
  unsigned ua = __float_as_uint(a), ub = __float_as_uint(b);
  ua += 0x7fffu + ((ua >> 16) & 1u);
  ub += 0x7fffu + ((ub >> 16) & 1u);
  return (ua >> 16) | (ub & 0xffff0000u);
}
// 1-instruction truncation pack via v_perm_b32 (exact for 0/1; ok for alpha)
__device__ __forceinline__ unsigned pktrunc(float lo, float hi) {
  return __builtin_amdgcn_perm(__float_as_uint(hi), __float_as_uint(lo), 0x07060302u);
}
__device__ __forceinline__ v4s mk4(unsigned lo, unsigned hi) {
  union { unsigned u[2]; v4s s; } z;
  z.u[0] = lo; z.u[1] = hi; return z.s;
}
__device__ __forceinline__ float bf_lo(unsigned u) { return __uint_as_float(u << 16); }
__device__ __forceinline__ float bf_hi(unsigned u) { return __uint_as_float(u & 0xffff0000u); }

__device__ __forceinline__ v4f mfma16(v4s a, v4s b, v4f c) {
  return __builtin_amdgcn_mfma_f32_16x16x16bf16_1k(a, b, c, 0, 0, 0);
}
__device__ __forceinline__ float fexp2(float x) {
#if __has_builtin(__builtin_amdgcn_exp2f)
  return __builtin_amdgcn_exp2f(x);
#else
  return exp2f(x);
#endif
}
__device__ __forceinline__ float rdlane(float v, int idx) {
  return __uint_as_float(__builtin_amdgcn_readlane(__float_as_uint(v), idx));
}

// E LDS index (u2 = 8B units) for (t_local in [0,32), x, wblk)
__device__ __forceinline__ int eidx(int tl, int x, int wblk) {
  return tl * 64 + x * 4 + (wblk ^ (x >> 2));
}

__global__ __launch_bounds__(64, 1) void fhmm_seg(
    const float* __restrict__ seq,     // [B, T, D]
    const int*   __restrict__ lengths, // [B]
    const float* __restrict__ pw,      // [16,16]
    const float* __restrict__ px,      // [16,16]
    const float* __restrict__ py,      // [16,16,64]
    float*       __restrict__ part,    // [2B] per-segment partials (log2 units)
    u2*          __restrict__ wsdif)   // [16*4*64] B-frag table (shared, 32 KB)
{
  const int bid = blockIdx.x;
  const int b = bid >> 1;
  const int p = bid & 1;
  const int l = threadIdx.x;
  const int g = l >> 4;
  const int x = l & 15;

  const int len = lengths[b];
  int mid = ((len + 32) >> 1) & ~31;   // chunk-aligned split point
  if (mid < 32) mid = 32;
  const bool split = (mid < len);

  if (p == 1 && !split) {              // short sequence: p0 does everything
    if (l == 0) part[bid] = 0.f;
    return;
  }

  __shared__ u2    Elds[32 * 64];      // ONE 32-step chunk: 32 t × 256 s bf16
  __shared__ __align__(16) float MxT[32 * 20];  // M transpose pad
  // total LDS = 16384 + 2560 = 18944 -> 8 blocks/CU with headroom

  // ---------- init: write dif B-frag table to ws; per-state base ----------
  float bfull[16];
#pragma unroll
  for (int st = 0; st < 16; ++st) {
    float pt = 0.f;
#pragma unroll
    for (int c = 0; c < 4; ++c) {
      f4 pv = *(const f4*)(py + (st * 16 + x) * 64 + c * 16 + g * 4);
      float q0 = __log2f(1.f - pv.x), q1 = __log2f(1.f - pv.y),
            q2 = __log2f(1.f - pv.z), q3 = __log2f(1.f - pv.w);
      pt += (q0 + q1) + (q2 + q3);
      u2 wv;
      wv.x = pk_bf16(__log2f(pv.x) - q0, __log2f(pv.y) - q1);
      wv.y = pk_bf16(__log2f(pv.z) - q2, __log2f(pv.w) - q3);
      wsdif[(st * 4 + c) * 64 + l] = wv;   // all blocks write identical bytes
    }
    pt += __shfl_xor(pt, 16, 64);
    pt += __shfl_xor(pt, 32, 64);
    bfull[st] = pt;   // base[st*16 + x]
  }

  v4s pwB, pxB;
  {
    const int r0 = (4 * g) * 16 + x;
    pwB = mk4(pk_bf16(pw[r0], pw[r0 + 16]), pk_bf16(pw[r0 + 32], pw[r0 + 48]));
    pxB = mk4(pk_bf16(px[r0], px[r0 + 16]), pk_bf16(px[r0 + 32], px[r0 + 48]));
  }
  const float p0w0 = pw[4 * g + 0], p0w1 = pw[4 * g + 1],
              p0w2 = pw[4 * g + 2], p0w3 = pw[4 * g + 3];
  const float px0 = px[x];

  const int t_acc  = p ? mid : 0;                       // first accounted step
  const int t_stop = p ? len : (split ? mid : len);     // one-past-last step
  const int c_lo   = p ? ((mid - 32) >> 5) : 0;
  const int c_hi   = (t_stop + 31) >> 5;

  const float* yb = seq + (size_t)b * (Tt * Dd);

  float acc  = 0.f;                     // log2 of accounted renorm factors
  float msum = 0.f;                     // accounted max-shift sum (per-lane)
  v4f al;                               // alpha (w=4g+id regs, x lanes)
  al[0] = al[1] = al[2] = al[3] = (p ? 1.f : 0.f);   // p1: uniform warmup init
  const v4f z4 = {0.f, 0.f, 0.f, 0.f};

#pragma unroll 1
  for (int ch = c_lo; ch < c_hi; ++ch) {
    const int tb = ch * 32;
    const float accf = (tb >= t_acc) ? 1.0f : 0.0f;   // warmup chunk: 0

    // ======== chunk GEMM: E'[t][s] = base[s] + sum_d y[t][d] dif[s][d] ======
    v4s ya16[2][4];
#pragma unroll
    for (int mt = 0; mt < 2; ++mt) {
      const float* yp = yb + (size_t)(tb + mt * 16 + x) * 64 + g * 4;
      f4 y0 = *(const f4*)(yp + 0);
      f4 y1 = *(const f4*)(yp + 16);
      f4 y2 = *(const f4*)(yp + 32);
      f4 y3 = *(const f4*)(yp + 48);
      ya16[mt][0] = mk4(pktrunc(y0.x, y0.y), pktrunc(y0.z, y0.w));
      ya16[mt][1] = mk4(pktrunc(y1.x, y1.y), pktrunc(y1.z, y1.w));
      ya16[mt][2] = mk4(pktrunc(y2.x, y2.y), pktrunc(y2.z, y2.w));
      ya16[mt][3] = mk4(pktrunc(y3.x, y3.y), pktrunc(y3.z, y3.w));
    }
    float mx[2][4];
#pragma unroll
    for (int mt = 0; mt < 2; ++mt)
#pragma unroll
      for (int id = 0; id < 4; ++id) mx[mt][id] = -1e30f;

#pragma unroll
    for (int q = 0; q < 4; ++q) {
      u2 Bq[4][4];
#pragma unroll
      for (int j = 0; j < 4; ++j)
#pragma unroll
        for (int c = 0; c < 4; ++c)
          Bq[j][c] = wsdif[(((q * 4 + j) * 4 + c)) * 64 + l];
      const float b0 = bfull[4 * q + 0], b1 = bfull[4 * q + 1],
                  b2 = bfull[4 * q + 2], b3 = bfull[4 * q + 3];
#pragma unroll
      for (int mt = 0; mt < 2; ++mt) {
        v4f a0 = z4, a1 = z4, a2 = z4, a3 = z4;
#pragma unroll
        for (int c = 0; c < 4; ++c) {
          a0 = mfma16(ya16[mt][c], mk4(Bq[0][c].x, Bq[0][c].y), a0);
          a1 = mfma16(ya16[mt][c], mk4(Bq[1][c].x, Bq[1][c].y), a1);
          a2 = mfma16(ya16[mt][c], mk4(Bq[2][c].x, Bq[2][c].y), a2);
          a3 = mfma16(ya16[mt][c], mk4(Bq[3][c].x, Bq[3][c].y), a3);
        }
#pragma unroll
        for (int id = 0; id < 4; ++id) {
          const float e0 = a0[id] + b0, e1 = a1[id] + b1,
                      e2 = a2[id] + b2, e3 = a3[id] + b3;
          u2 wv;
          wv.x = pk_bf16(e0, e1);
          wv.y = pk_bf16(e2, e3);
          Elds[eidx(mt * 16 + 4 * g + id, x, q)] = wv;
          const float mq = fmaxf(fmaxf(e0, e1), fmaxf(e2, e3));
          mx[mt][id] = fmaxf(mx[mt][id], mq);
        }
      }
    }
    // M'[t] = max_s E' via LDS transpose; lane l holds M[tb + (l&31)]
#pragma unroll
    for (int mt = 0; mt < 2; ++mt)
#pragma unroll
      for (int id = 0; id < 4; ++id)
        MxT[(mt * 16 + 4 * g + id) * 20 + x] = mx[mt][id];
    __syncthreads();
    float Mrow;
    {
      const f4* row = (const f4*)&MxT[(l & 31) * 20];
      f4 r0 = row[0], r1 = row[1], r2 = row[2], r3 = row[3];
      const float m01 = fmaxf(fmaxf(r0.x, r0.y), fmaxf(r0.z, r0.w));
      const float m23 = fmaxf(fmaxf(r1.x, r1.y), fmaxf(r1.z, r1.w));
      const float m45 = fmaxf(fmaxf(r2.x, r2.y), fmaxf(r2.z, r2.w));
      const float m67 = fmaxf(fmaxf(r3.x, r3.y), fmaxf(r3.z, r3.w));
      Mrow = fmaxf(fmaxf(m01, m23), fmaxf(m45, m67));
    }
    // inline accounted msum (lanes 0..31 only; upper half duplicates Mrow)
    {
      const int tm = tb + (l & 31);
      if (l < 32 && tm >= t_acc && tm < t_stop) msum += Mrow;
    }

    // ======== scan phase: steps t in [tb, te) ========
    const int te = (t_stop < tb + 32) ? t_stop : (tb + 32);
    int t = tb;
    u2 Ec = Elds[eidx(0, x, g)];

#define SCAN_STEP(TCUR, PF)                                                 \
    {                                                                       \
      u2 En_ = Ec;                                                          \
      PF                                                                    \
      const float Ms_ = rdlane(Mrow, (TCUR) & 31);                          \
      const float e0 = fexp2(bf_lo(Ec.x) - Ms_);                            \
      const float e1 = fexp2(bf_hi(Ec.x) - Ms_);                            \
      const float e2 = fexp2(bf_lo(Ec.y) - Ms_);                            \
      const float e3 = fexp2(bf_hi(Ec.y) - Ms_);                            \
      v4s a16 = mk4(pktrunc(al[0], al[1]), pktrunc(al[2], al[3]));          \
      v4f d1 = mfma16(a16, pwB, z4);                                        \
      v4s d16 = mk4(pktrunc(d1[0], d1[1]), pktrunc(d1[2], d1[3]));          \
      v4f d2 = mfma16(d16, pxB, z4);                                        \
      al[0] = d2[0] * e0; al[1] = d2[1] * e1;                               \
      al[2] = d2[2] * e2; al[3] = d2[3] * e3;                               \
      Ec = En_;                                                             \
    }

#define RENORM                                                              \
    {                                                                       \
      float S = (al[0] + al[1]) + (al[2] + al[3]);                          \
      _Pragma("unroll")                                                     \
      for (int o = 1; o <= 32; o <<= 1) S += __shfl_xor(S, o, 64);          \
      S = fmaxf(S, 1e-35f);                                                 \
      const float r = __builtin_amdgcn_rcpf(S);                             \
      al[0] *= r; al[1] *= r; al[2] *= r; al[3] *= r;                       \
      acc += accf * __log2f(S);                                             \
    }

    if (p == 0 && ch == 0) {   // peel t = 0: alpha0 = prior * e
      const float Ms_ = rdlane(Mrow, 0);
      const float e0 = fexp2(bf_lo(Ec.x) - Ms_);
      const float e1 = fexp2(bf_hi(Ec.x) - Ms_);
      const float e2 = fexp2(bf_lo(Ec.y) - Ms_);
      const float e3 = fexp2(bf_hi(Ec.y) - Ms_);
      al[0] = p0w0 * px0 * e0; al[1] = p0w1 * px0 * e1;
      al[2] = p0w2 * px0 * e2; al[3] = p0w3 * px0 * e3;
      t = 1;
      if (t < te) Ec = Elds[eidx(1, x, g)];
    }

    while (t < te && (t & 7)) {     // guarded entry until 8-aligned
      SCAN_STEP(t,
        if (t + 1 < te) { En_ = Elds[eidx((t + 1) & 31, x, g)]; })
      if ((t & 7) == 7) RENORM
      ++t;
    }

    // fast path: 8-step groups, depth-2 E prefetch, pipelined shfl renorm
    const int ng = (te - t) >> 3;
    if (ng > 0) {
      u2 E1 = Elds[eidx((t + 1) & 31, x, g)];
      float snap = 0.f, Sready = 1.0f, rdy = 1.0f;
#pragma unroll 1
      for (int gi = 0; gi < ng; ++gi) {
#pragma unroll
        for (int k = 0; k < 8; ++k) {
          u2 E2 = Elds[eidx((t + k + 2) & 31, x, g)];   // 2-deep prefetch
          const float Ms_ = rdlane(Mrow, (t + k) & 31);
          float e0 = fexp2(bf_lo(Ec.x) - Ms_);
          float e1 = fexp2(bf_hi(Ec.x) - Ms_);
          float e2 = fexp2(bf_lo(Ec.y) - Ms_);
          float e3 = fexp2(bf_hi(Ec.y) - Ms_);
          if (k == 0) {       // apply previous group's renorm (off chain)
            e0 *= rdy; e1 *= rdy; e2 *= rdy; e3 *= rdy;
            acc += accf * __log2f(Sready);
          }
          v4s a16 = mk4(pktrunc(al[0], al[1]), pktrunc(al[2], al[3]));
          v4f d1 = mfma16(a16, pwB, z4);
          v4s d16 = mk4(pktrunc(d1[0], d1[1]), pktrunc(d1[2], d1[3]));
          v4f d2 = mfma16(d16, pxB, z4);
          al[0] = d2[0] * e0; al[1] = d2[1] * e1;
          al[2] = d2[2] * e2; al[3] = d2[3] * e3;
          if (k == 0) snap = (al[0] + al[1]) + (al[2] + al[3]);  // snapshot
          if (k >= 1 && k <= 6)                                   // 1 hop/step
            snap += __shfl_xor(snap, 1 << (k - 1), 64);
          if (k == 7) {                                           // ready
            Sready = fmaxf(snap, 1e-35f);
            rdy = __builtin_amdgcn_rcpf(Sready);
          }
          Ec = E1; E1 = E2;
        }
        t += 8;
      }
      acc += accf * __log2f(Sready);     // flush pending renorm
      al[0] *= rdy; al[1] *= rdy; al[2] *= rdy; al[3] *= rdy;
    }

    while (t < te) {                // guarded tail (final chunk only)
      SCAN_STEP(t,
        if (t + 1 < te) { En_ = Elds[eidx((t + 1) & 31, x, g)]; })
      if ((t & 7) == 7) RENORM
      ++t;
    }
#undef SCAN_STEP
#undef RENORM

    __syncthreads();   // scan reads done -> next chunk GEMM may overwrite
  }

  // ---------- finalize: fold final mass (always accounted) + msum ----------
  float S = (al[0] + al[1]) + (al[2] + al[3]);
#pragma unroll
  for (int o = 1; o <= 32; o <<= 1) S += __shfl_xor(S, o, 64);
  S = fmaxf(S, 1e-35f);
  acc += __log2f(S);

#pragma unroll
  for (int o = 1; o <= 32; o <<= 1) msum += __shfl_xor(msum, o, 64);

  if (l == 0) part[bid] = acc + msum;
}

__global__ void fhmm_reduce(const float* __restrict__ part,
                            float* __restrict__ out) {
  const int i = blockIdx.x * 256 + threadIdx.x;   // 4 blocks x 256 = 1024
  out[i] = LN2 * (part[2 * i] + part[2 * i + 1]);
}

} // namespace

extern "C" void kernel_launch(void* const* d_in, const int* in_sizes, int n_in,
                              void* d_out, int out_size, void* d_ws, size_t ws_size,
                              hipStream_t stream) {
  const float* seq     = (const float*)d_in[0];
  const int*   lengths = (const int*)d_in[1];
  const float* pw      = (const float*)d_in[2];
  const float* px      = (const float*)d_in[3];
  const float* py      = (const float*)d_in[4];
  float*       out     = (float*)d_out;
  u2*          wsdif   = (u2*)d_ws;                         // 32 KB table
  float*       part    = (float*)((char*)d_ws + 32768);     // 8 KB partials

  hipLaunchKernelGGL(fhmm_seg, dim3(2048), dim3(64), 0, stream,
                     seq, lengths, pw, px, py, part, wsdif);
  hipLaunchKernelGGL(fhmm_reduce, dim3(4), dim3(256), 0, stream, part, out);
}

// Round 15
// 135.506 us; speedup vs baseline: 1.0390x; 1.0390x over previous
//
#include <hip/hip_runtime.h>

namespace {

typedef short    v4s __attribute__((ext_vector_type(4)));
typedef float    v4f __attribute__((ext_vector_type(4)));
typedef float    f4  __attribute__((ext_vector_type(4)));
typedef unsigned u2  __attribute__((ext_vector_type(2)));

constexpr int Tt = 512;
constexpr int Dd = 64;
constexpr float LN2 = 0.69314718055994530942f;

__device__ __forceinline__ unsigned pk_bf16(float a, float b) {
  unsigned ua = __float_as_uint(a), ub = __float_as_uint(b);
  ua += 0x7fffu + ((ua >> 16) & 1u);
  ub += 0x7fffu + ((ub >> 16) & 1u);
  return (ua >> 16) | (ub & 0xffff0000u);
}
__device__ __forceinline__ unsigned pktrunc(float lo, float hi) {
  return __builtin_amdgcn_perm(__float_as_uint(hi), __float_as_uint(lo), 0x07060302u);
}
__device__ __forceinline__ v4s mk4(unsigned lo, unsigned hi) {
  union { unsigned u[2]; v4s s; } z;
  z.u[0] = lo; z.u[1] = hi; return z.s;
}
__device__ __forceinline__ float bf_lo(unsigned u) { return __uint_as_float(u << 16); }
__device__ __forceinline__ float bf_hi(unsigned u) { return __uint_as_float(u & 0xffff0000u); }

__device__ __forceinline__ v4f mfma16(v4s a, v4s b, v4f c) {
  return __builtin_amdgcn_mfma_f32_16x16x16bf16_1k(a, b, c, 0, 0, 0);
}
__device__ __forceinline__ float fexp2(float x) {
#if __has_builtin(__builtin_amdgcn_exp2f)
  return __builtin_amdgcn_exp2f(x);
#else
  return exp2f(x);
#endif
}
__device__ __forceinline__ float rdlane(float v, int idx) {
  return __uint_as_float(__builtin_amdgcn_readlane(__float_as_uint(v), idx));
}

// E LDS index (u2 = 8B units) for (t_local in [0,64), x, wblk)
__device__ __forceinline__ int eidx(int tl, int x, int wblk) {
  return tl * 64 + x * 4 + (wblk ^ (x >> 2));
}

__global__ __launch_bounds__(64, 1) void fhmm_fwd(
    const float* __restrict__ seq,     // [B, T, D]
    const int*   __restrict__ lengths, // [B]
    const float* __restrict__ pw,      // [16,16]
    const float* __restrict__ px,      // [16,16]
    const float* __restrict__ py,      // [16,16,64]
    float*       __restrict__ out,     // [B]
    u2*          __restrict__ wsdif)   // [16*4*64] B-frag table (shared, 32 KB)
{
  const int b = blockIdx.x;
  const int l = threadIdx.x;
  const int g = l >> 4;
  const int x = l & 15;

  __shared__ u2    Elds[64 * 64];               // 64 t × 256 s, bf16(E') pairs
  __shared__ __align__(16) float MxT[64 * 20];  // M transpose pad
  // LDS total = 32768 + 5120 = 37888 -> 4 blocks/CU

  // ---------- init: dif B-frag table to ws; per-state base ----------
  float bfull[16];
#pragma unroll
  for (int st = 0; st < 16; ++st) {
    float pt = 0.f;
#pragma unroll
    for (int c = 0; c < 4; ++c) {
      f4 pv = *(const f4*)(py + (st * 16 + x) * 64 + c * 16 + g * 4);
      float q0 = __log2f(1.f - pv.x), q1 = __log2f(1.f - pv.y),
            q2 = __log2f(1.f - pv.z), q3 = __log2f(1.f - pv.w);
      pt += (q0 + q1) + (q2 + q3);
      u2 wv;
      wv.x = pk_bf16(__log2f(pv.x) - q0, __log2f(pv.y) - q1);
      wv.y = pk_bf16(__log2f(pv.z) - q2, __log2f(pv.w) - q3);
      wsdif[(st * 4 + c) * 64 + l] = wv;   // all blocks write identical bytes
    }
    pt += __shfl_xor(pt, 16, 64);
    pt += __shfl_xor(pt, 32, 64);
    bfull[st] = pt;   // base[st*16 + x]
  }

  v4s pwB, pxB;
  {
    const int r0 = (4 * g) * 16 + x;
    pwB = mk4(pk_bf16(pw[r0], pw[r0 + 16]), pk_bf16(pw[r0 + 32], pw[r0 + 48]));
    pxB = mk4(pk_bf16(px[r0], px[r0 + 16]), pk_bf16(px[r0 + 32], px[r0 + 48]));
  }
  const float p0w0 = pw[4 * g + 0], p0w1 = pw[4 * g + 1],
              p0w2 = pw[4 * g + 2], p0w3 = pw[4 * g + 3];
  const float px0 = px[x];

  const int len = lengths[b];
  const int nch = (len + 63) >> 6;
  const float* yb = seq + (size_t)b * (Tt * Dd);

  float acc  = 0.f;
  float msum = 0.f;
  v4f al = {0.f, 0.f, 0.f, 0.f};
  const v4f z4 = {0.f, 0.f, 0.f, 0.f};

  f4  pf[8];        // in-flight y prefetch (8 x f4 = 32 VGPR, transient)
  v4s yp16[16];     // packed next-chunk A-frags (32 VGPR)

// issue 8 f4 loads for rows mt (MT0) and mt+1 (MT0+1) of chunk at TB
#define PF_ISSUE(TB, MT0)                                                   \
    _Pragma("unroll")                                                       \
    for (int m_ = 0; m_ < 2; ++m_)                                          \
      _Pragma("unroll")                                                     \
      for (int c_ = 0; c_ < 4; ++c_)                                        \
        pf[m_ * 4 + c_] = *(const f4*)(yb +                                 \
            (size_t)((TB) + ((MT0) + m_) * 16 + x) * 64 + c_ * 16 + g * 4);

#define PF_PACK(MT0)                                                        \
    _Pragma("unroll")                                                       \
    for (int i_ = 0; i_ < 8; ++i_)                                          \
      yp16[(MT0) * 4 + i_] = mk4(pktrunc(pf[i_].x, pf[i_].y),               \
                                 pktrunc(pf[i_].z, pf[i_].w));

#define BQLOAD(DST, QN)                                                     \
    _Pragma("unroll")                                                       \
    for (int j_ = 0; j_ < 4; ++j_)                                          \
      _Pragma("unroll")                                                     \
      for (int c_ = 0; c_ < 4; ++c_)                                        \
        DST[j_ * 4 + c_] = wsdif[(((QN) * 4 + j_) * 4 + c_) * 64 + l];

#define GEMM_Q(BUF, QI)                                                     \
    {                                                                       \
      const float b0 = bfull[4 * (QI) + 0], b1 = bfull[4 * (QI) + 1],       \
                  b2 = bfull[4 * (QI) + 2], b3 = bfull[4 * (QI) + 3];       \
      _Pragma("unroll")                                                     \
      for (int mt_ = 0; mt_ < 4; ++mt_) {                                   \
        v4f a0 = z4, a1 = z4, a2 = z4, a3 = z4;                             \
        _Pragma("unroll")                                                   \
        for (int c_ = 0; c_ < 4; ++c_) {                                    \
          a0 = mfma16(ya16[mt_ * 4 + c_], mk4(BUF[c_].x,      BUF[c_].y),      a0); \
          a1 = mfma16(ya16[mt_ * 4 + c_], mk4(BUF[4 + c_].x,  BUF[4 + c_].y),  a1); \
          a2 = mfma16(ya16[mt_ * 4 + c_], mk4(BUF[8 + c_].x,  BUF[8 + c_].y),  a2); \
          a3 = mfma16(ya16[mt_ * 4 + c_], mk4(BUF[12 + c_].x, BUF[12 + c_].y), a3); \
        }                                                                   \
        _Pragma("unroll")                                                   \
        for (int id_ = 0; id_ < 4; ++id_) {                                 \
          const float e0 = a0[id_] + b0, e1 = a1[id_] + b1,                 \
                      e2 = a2[id_] + b2, e3 = a3[id_] + b3;                 \
          u2 wv;                                                            \
          wv.x = pk_bf16(e0, e1);                                           \
          wv.y = pk_bf16(e2, e3);                                           \
          Elds[eidx(mt_ * 16 + 4 * g + id_, x, (QI))] = wv;                 \
          const float mq = fmaxf(fmaxf(e0, e1), fmaxf(e2, e3));             \
          mx[mt_][id_] = fmaxf(mx[mt_][id_], mq);                           \
        }                                                                   \
      }                                                                     \
    }

#pragma unroll 1
  for (int ch = 0; ch < nch; ++ch) {
    const int tb = ch * 64;

    // ======== chunk GEMM: E'[t][s] = base[s] + sum_d y[t][d] dif[s][d] ======
    v4s ya16[16];
    if (ch == 0) {      // cold first chunk: load + pack inline
#pragma unroll
      for (int mt = 0; mt < 4; mt += 2) { PF_ISSUE(0, mt) PF_PACK(mt) }
#pragma unroll
      for (int i = 0; i < 16; ++i) ya16[i] = yp16[i];
    } else {            // prefetched during previous chunk's scan
#pragma unroll
      for (int i = 0; i < 16; ++i) ya16[i] = yp16[i];
    }

    float mx[4][4];
#pragma unroll
    for (int mt = 0; mt < 4; ++mt)
#pragma unroll
      for (int id = 0; id < 4; ++id) mx[mt][id] = -1e30f;

    // Bq depth-2 pipeline: both buffers in flight before first use
    u2 BqA[16], BqB[16];
    BQLOAD(BqA, 0)
    BQLOAD(BqB, 1)
    GEMM_Q(BqA, 0)
    BQLOAD(BqA, 2)
    GEMM_Q(BqB, 1)
    BQLOAD(BqB, 3)
    GEMM_Q(BqA, 2)
    GEMM_Q(BqB, 3)

    // M'[t] = max_s E' via LDS transpose; lane l holds M[tb + l]
#pragma unroll
    for (int mt = 0; mt < 4; ++mt)
#pragma unroll
      for (int id = 0; id < 4; ++id)
        MxT[(mt * 16 + 4 * g + id) * 20 + x] = mx[mt][id];
    __syncthreads();
    float Mrow;
    {
      const f4* row = (const f4*)&MxT[l * 20];
      f4 r0 = row[0], r1 = row[1], r2 = row[2], r3 = row[3];
      const float m01 = fmaxf(fmaxf(r0.x, r0.y), fmaxf(r0.z, r0.w));
      const float m23 = fmaxf(fmaxf(r1.x, r1.y), fmaxf(r1.z, r1.w));
      const float m45 = fmaxf(fmaxf(r2.x, r2.y), fmaxf(r2.z, r2.w));
      const float m67 = fmaxf(fmaxf(r3.x, r3.y), fmaxf(r3.z, r3.w));
      Mrow = fmaxf(fmaxf(m01, m23), fmaxf(m45, m67));
    }
    if (tb + l < len) msum += Mrow;   // inline accounted max-shift sum

    __syncthreads();   // GEMM + M writes -> scan reads

    // ======== scan phase: steps t in [tb, te) ========
    const int te = (len < tb + 64) ? len : (tb + 64);
    const bool nextch = (tb + 64 < len);   // prefetch target exists
    int t = tb;
    u2 Ec = Elds[eidx(0, x, g)];

#define SCAN_STEP(TCUR, PF)                                                 \
    {                                                                       \
      u2 En_ = Ec;                                                          \
      PF                                                                    \
      const float Ms_ = rdlane(Mrow, (TCUR) & 63);                          \
      const float e0 = fexp2(bf_lo(Ec.x) - Ms_);                            \
      const float e1 = fexp2(bf_hi(Ec.x) - Ms_);                            \
      const float e2 = fexp2(bf_lo(Ec.y) - Ms_);                            \
      const float e3 = fexp2(bf_hi(Ec.y) - Ms_);                            \
      v4s a16 = mk4(pktrunc(al[0], al[1]), pktrunc(al[2], al[3]));          \
      v4f d1 = mfma16(a16, pwB, z4);                                        \
      v4s d16 = mk4(pktrunc(d1[0], d1[1]), pktrunc(d1[2], d1[3]));          \
      v4f d2 = mfma16(d16, pxB, z4);                                        \
      al[0] = d2[0] * e0; al[1] = d2[1] * e1;                               \
      al[2] = d2[2] * e2; al[3] = d2[3] * e3;                               \
      Ec = En_;                                                             \
    }

#define RENORM                                                              \
    {                                                                       \
      float S = (al[0] + al[1]) + (al[2] + al[3]);                          \
      _Pragma("unroll")                                                     \
      for (int o = 1; o <= 32; o <<= 1) S += __shfl_xor(S, o, 64);          \
      S = fmaxf(S, 1e-35f);                                                 \
      const float r = __builtin_amdgcn_rcpf(S);                             \
      al[0] *= r; al[1] *= r; al[2] *= r; al[3] *= r;                       \
      acc += __log2f(S);                                                    \
    }

    if (ch == 0) {   // peel t = 0: alpha0 = prior * e
      const float Ms_ = rdlane(Mrow, 0);
      const float e0 = fexp2(bf_lo(Ec.x) - Ms_);
      const float e1 = fexp2(bf_hi(Ec.x) - Ms_);
      const float e2 = fexp2(bf_lo(Ec.y) - Ms_);
      const float e3 = fexp2(bf_hi(Ec.y) - Ms_);
      al[0] = p0w0 * px0 * e0; al[1] = p0w1 * px0 * e1;
      al[2] = p0w2 * px0 * e2; al[3] = p0w3 * px0 * e3;
      t = 1;
      if (t < te) Ec = Elds[eidx(1, x, g)];
    }

    while (t < te && (t & 7)) {     // guarded entry until 8-aligned
      SCAN_STEP(t,
        if (t + 1 < te) { En_ = Elds[eidx((t + 1) & 63, x, g)]; })
      if ((t & 7) == 7) RENORM
      ++t;
    }

    // fast path: 8-step groups; y prefetch for chunk ch+1 at group seams
    const int ng = (te - t) >> 3;
    if (ng > 0) {
      u2 E1 = Elds[eidx((t + 1) & 63, x, g)];
      float snap = 0.f, Sready = 1.0f, rdy = 1.0f;
#pragma unroll 1
      for (int gi = 0; gi < ng; ++gi) {
        if (nextch) {                       // uniform, off critical path
          if (gi == 0) { PF_ISSUE(tb + 64, 0) }
          if (gi == 2) { PF_PACK(0) PF_ISSUE(tb + 64, 2) }
          if (gi == 5) { PF_PACK(2) }
        }
#pragma unroll
        for (int k = 0; k < 8; ++k) {
          u2 E2 = Elds[eidx((t + k + 2) & 63, x, g)];   // 2-deep prefetch
          const float Ms_ = rdlane(Mrow, (t + k) & 63);
          float e0 = fexp2(bf_lo(Ec.x) - Ms_);
          float e1 = fexp2(bf_hi(Ec.x) - Ms_);
          float e2 = fexp2(bf_lo(Ec.y) - Ms_);
          float e3 = fexp2(bf_hi(Ec.y) - Ms_);
          if (k == 0) {       // apply previous group's renorm (off chain)
            e0 *= rdy; e1 *= rdy; e2 *= rdy; e3 *= rdy;
            acc += __log2f(Sready);
          }
          v4s a16 = mk4(pktrunc(al[0], al[1]), pktrunc(al[2], al[3]));
          v4f d1 = mfma16(a16, pwB, z4);
          v4s d16 = mk4(pktrunc(d1[0], d1[1]), pktrunc(d1[2], d1[3]));
          v4f d2 = mfma16(d16, pxB, z4);
          al[0] = d2[0] * e0; al[1] = d2[1] * e1;
          al[2] = d2[2] * e2; al[3] = d2[3] * e3;
          if (k == 0) snap = (al[0] + al[1]) + (al[2] + al[3]);
          if (k >= 1 && k <= 6)
            snap += __shfl_xor(snap, 1 << (k - 1), 64);
          if (k == 7) {
            Sready = fmaxf(snap, 1e-35f);
            rdy = __builtin_amdgcn_rcpf(Sready);
          }
          Ec = E1; E1 = E2;
        }
        t += 8;
      }
      acc += __log2f(Sready);     // flush pending renorm
      al[0] *= rdy; al[1] *= rdy; al[2] *= rdy; al[3] *= rdy;
    }

    while (t < te) {                // guarded tail (final chunk only)
      SCAN_STEP(t,
        if (t + 1 < te) { En_ = Elds[eidx((t + 1) & 63, x, g)]; })
      if ((t & 7) == 7) RENORM
      ++t;
    }
#undef SCAN_STEP
#undef RENORM

    __syncthreads();   // scan reads done -> next chunk GEMM may overwrite
  }

  // ---------- finalize ----------
  float S = (al[0] + al[1]) + (al[2] + al[3]);
#pragma unroll
  for (int o = 1; o <= 32; o <<= 1) S += __shfl_xor(S, o, 64);
  S = fmaxf(S, 1e-35f);
  acc += __log2f(S);

#pragma unroll
  for (int o = 1; o <= 32; o <<= 1) msum += __shfl_xor(msum, o, 64);

  if (l == 0) out[b] = LN2 * (acc + msum);
}

} // namespace

extern "C" void kernel_launch(void* const* d_in, const int* in_sizes, int n_in,
                              void* d_out, int out_size, void* d_ws, size_t ws_size,
                              hipStream_t stream) {
  const float* seq     = (const float*)d_in[0];
  const int*   lengths = (const int*)d_in[1];
  const float* pw      = (const float*)d_in[2];
  const float* px      = (const float*)d_in[3];
  const float* py      = (const float*)d_in[4];
  float*       out     = (float*)d_out;
  u2*          wsdif   = (u2*)d_ws;    // 32 KB shared B-frag table

  hipLaunchKernelGGL(fhmm_fwd, dim3(1024), dim3(64), 0, stream,
                     seq, lengths, pw, px, py, out, wsdif);
}

// Round 16
// 91.754 us; speedup vs baseline: 1.5344x; 1.4768x over previous
//
#include <hip/hip_runtime.h>

namespace {

typedef short    v4s __attribute__((ext_vector_type(4)));
typedef float    v4f __attribute__((ext_vector_type(4)));
typedef float    f4  __attribute__((ext_vector_type(4)));
typedef unsigned u2  __attribute__((ext_vector_type(2)));

constexpr int Tt = 512;
constexpr int Dd = 64;
constexpr int CH = 32;            // chunk length (steps)
constexpr float LN2 = 0.69314718055994530942f;

__device__ __forceinline__ unsigned pk_bf16(float a, float b) {
  unsigned ua = __float_as_uint(a), ub = __float_as_uint(b);
  ua += 0x7fffu + ((ua >> 16) & 1u);
  ub += 0x7fffu + ((ub >> 16) & 1u);
  return (ua >> 16) | (ub & 0xffff0000u);
}
__device__ __forceinline__ unsigned pktrunc(float lo, float hi) {
  return __builtin_amdgcn_perm(__float_as_uint(hi), __float_as_uint(lo), 0x07060302u);
}
__device__ __forceinline__ v4s mk4(unsigned lo, unsigned hi) {
  union { unsigned u[2]; v4s s; } z;
  z.u[0] = lo; z.u[1] = hi; return z.s;
}
__device__ __forceinline__ float bf_lo(unsigned u) { return __uint_as_float(u << 16); }
__device__ __forceinline__ float bf_hi(unsigned u) { return __uint_as_float(u & 0xffff0000u); }

__device__ __forceinline__ v4f mfma16(v4s a, v4s b, v4f c) {
  return __builtin_amdgcn_mfma_f32_16x16x16bf16_1k(a, b, c, 0, 0, 0);
}
__device__ __forceinline__ float fexp2(float x) {
#if __has_builtin(__builtin_amdgcn_exp2f)
  return __builtin_amdgcn_exp2f(x);
#else
  return exp2f(x);
#endif
}
__device__ __forceinline__ float rdlane(float v, int idx) {
  return __uint_as_float(__builtin_amdgcn_readlane(__float_as_uint(v), idx));
}

// E LDS index (u2 = 8B units) for (t_local in [0,32), x, wblk)
__device__ __forceinline__ int eidx(int tl, int x, int wblk) {
  return tl * 64 + x * 4 + (wblk ^ (x >> 2));
}

__global__ __launch_bounds__(128, 1) void fhmm_fwd(
    const float* __restrict__ seq,     // [B, T, D]
    const int*   __restrict__ lengths, // [B]
    const float* __restrict__ pw,      // [16,16]
    const float* __restrict__ px,      // [16,16]
    const float* __restrict__ py,      // [16,16,64]
    float*       __restrict__ out,     // [B]
    u2*          __restrict__ wsdif)   // [16*4*64] B-frag table (shared, 32 KB)
{
  const int b   = blockIdx.x;
  const int tid = threadIdx.x;
  const int wv  = tid >> 6;            // 0 = consumer (scan), 1 = producer (GEMM)
  const int l   = tid & 63;
  const int g   = l >> 4;
  const int x   = l & 15;

  __shared__ u2    Elds[2][CH * 64];           // double-buffered E' (2 × 16 KB)
  __shared__ float Mbufs[2][32];               // per-chunk max shifts
  __shared__ __align__(16) float MxT[CH * 20]; // producer-private transpose pad
  // LDS total = 32768 + 256 + 2560 = 35584 -> 4 blocks/CU (8 waves/CU)

  const int len = lengths[b];
  const int nch = (len + CH - 1) >> 5;
  const float* yb = seq + (size_t)b * (Tt * Dd);

  if (wv == 1) {
    // ==================== PRODUCER WAVE ====================
    float bfull[16];
#pragma unroll
    for (int st = 0; st < 16; ++st) {
      float pt = 0.f;
#pragma unroll
      for (int c = 0; c < 4; ++c) {
        f4 pv = *(const f4*)(py + (st * 16 + x) * 64 + c * 16 + g * 4);
        float q0 = __log2f(1.f - pv.x), q1 = __log2f(1.f - pv.y),
              q2 = __log2f(1.f - pv.z), q3 = __log2f(1.f - pv.w);
        pt += (q0 + q1) + (q2 + q3);
        u2 wvv;
        wvv.x = pk_bf16(__log2f(pv.x) - q0, __log2f(pv.y) - q1);
        wvv.y = pk_bf16(__log2f(pv.z) - q2, __log2f(pv.w) - q3);
        wsdif[(st * 4 + c) * 64 + l] = wvv;   // all blocks write identical bytes
      }
      pt += __shfl_xor(pt, 16, 64);
      pt += __shfl_xor(pt, 32, 64);
      bfull[st] = pt;   // base[st*16 + x]
    }

#define GEMMCHUNK(CHIDX)                                                      \
    {                                                                         \
      const int tb_  = (CHIDX) * CH;                                          \
      const int buf_ = (CHIDX) & 1;                                           \
      v4s ya16[2][4];                                                         \
      _Pragma("unroll")                                                       \
      for (int mt_ = 0; mt_ < 2; ++mt_) {                                     \
        const float* yp_ = yb + (size_t)(tb_ + mt_ * 16 + x) * 64 + g * 4;    \
        f4 y0_ = *(const f4*)(yp_ + 0);                                       \
        f4 y1_ = *(const f4*)(yp_ + 16);                                      \
        f4 y2_ = *(const f4*)(yp_ + 32);                                      \
        f4 y3_ = *(const f4*)(yp_ + 48);                                      \
        ya16[mt_][0] = mk4(pktrunc(y0_.x, y0_.y), pktrunc(y0_.z, y0_.w));     \
        ya16[mt_][1] = mk4(pktrunc(y1_.x, y1_.y), pktrunc(y1_.z, y1_.w));     \
        ya16[mt_][2] = mk4(pktrunc(y2_.x, y2_.y), pktrunc(y2_.z, y2_.w));     \
        ya16[mt_][3] = mk4(pktrunc(y3_.x, y3_.y), pktrunc(y3_.z, y3_.w));     \
      }                                                                       \
      float mx_[2][4];                                                        \
      _Pragma("unroll")                                                       \
      for (int mt_ = 0; mt_ < 2; ++mt_)                                       \
        _Pragma("unroll")                                                     \
        for (int id_ = 0; id_ < 4; ++id_) mx_[mt_][id_] = -1e30f;             \
      _Pragma("unroll")                                                       \
      for (int q_ = 0; q_ < 4; ++q_) {                                        \
        u2 Bq_[16];                                                           \
        _Pragma("unroll")                                                     \
        for (int j_ = 0; j_ < 4; ++j_)                                        \
          _Pragma("unroll")                                                   \
          for (int c_ = 0; c_ < 4; ++c_)                                      \
            Bq_[j_ * 4 + c_] = wsdif[((q_ * 4 + j_) * 4 + c_) * 64 + l];      \
        const float b0_ = bfull[4 * q_ + 0], b1_ = bfull[4 * q_ + 1],         \
                    b2_ = bfull[4 * q_ + 2], b3_ = bfull[4 * q_ + 3];         \
        _Pragma("unroll")                                                     \
        for (int mt_ = 0; mt_ < 2; ++mt_) {                                   \
          v4f a0_ = z4, a1_ = z4, a2_ = z4, a3_ = z4;                         \
          _Pragma("unroll")                                                   \
          for (int c_ = 0; c_ < 4; ++c_) {                                    \
            a0_ = mfma16(ya16[mt_][c_], mk4(Bq_[c_].x,      Bq_[c_].y),      a0_); \
            a1_ = mfma16(ya16[mt_][c_], mk4(Bq_[4 + c_].x,  Bq_[4 + c_].y),  a1_); \
            a2_ = mfma16(ya16[mt_][c_], mk4(Bq_[8 + c_].x,  Bq_[8 + c_].y),  a2_); \
            a3_ = mfma16(ya16[mt_][c_], mk4(Bq_[12 + c_].x, Bq_[12 + c_].y), a3_); \
          }                                                                   \
          _Pragma("unroll")                                                   \
          for (int id_ = 0; id_ < 4; ++id_) {                                 \
            const float e0_ = a0_[id_] + b0_, e1_ = a1_[id_] + b1_,           \
                        e2_ = a2_[id_] + b2_, e3_ = a3_[id_] + b3_;           \
            u2 wv_;                                                           \
            wv_.x = pk_bf16(e0_, e1_);                                        \
            wv_.y = pk_bf16(e2_, e3_);                                        \
            Elds[buf_][eidx(mt_ * 16 + 4 * g + id_, x, q_)] = wv_;            \
            const float mq_ = fmaxf(fmaxf(e0_, e1_), fmaxf(e2_, e3_));        \
            mx_[mt_][id_] = fmaxf(mx_[mt_][id_], mq_);                        \
          }                                                                   \
        }                                                                     \
      }                                                                       \
      _Pragma("unroll")                                                       \
      for (int mt_ = 0; mt_ < 2; ++mt_)                                       \
        _Pragma("unroll")                                                     \
        for (int id_ = 0; id_ < 4; ++id_)                                     \
          MxT[(mt_ * 16 + 4 * g + id_) * 20 + x] = mx_[mt_][id_];             \
      {  /* same-wave LDS transpose read (no barrier needed) */               \
        const f4* row_ = (const f4*)&MxT[(l & 31) * 20];                      \
        f4 r0_ = row_[0], r1_ = row_[1], r2_ = row_[2], r3_ = row_[3];        \
        const float m01_ = fmaxf(fmaxf(r0_.x, r0_.y), fmaxf(r0_.z, r0_.w));  \
        const float m23_ = fmaxf(fmaxf(r1_.x, r1_.y), fmaxf(r1_.z, r1_.w));  \
        const float m45_ = fmaxf(fmaxf(r2_.x, r2_.y), fmaxf(r2_.z, r2_.w));  \
        const float m67_ = fmaxf(fmaxf(r3_.x, r3_.y), fmaxf(r3_.z, r3_.w));  \
        const float Mr_ = fmaxf(fmaxf(m01_, m23_), fmaxf(m45_, m67_));        \
        if (l < 32) Mbufs[buf_][l] = Mr_;                                     \
      }                                                                       \
    }

    const v4f z4 = {0.f, 0.f, 0.f, 0.f};
    GEMMCHUNK(0)
    __syncthreads();                       // buf0 ready
#pragma unroll 1
    for (int ch = 0; ch < nch; ++ch) {
      if (ch + 1 < nch) GEMMCHUNK(ch + 1)  // overlaps consumer's scan(ch)
      __syncthreads();                     // GEMM(ch+1) done & scan(ch) done
    }
#undef GEMMCHUNK

  } else {
    // ==================== CONSUMER WAVE ====================
    v4s pwB, pxB;
    {
      const int r0 = (4 * g) * 16 + x;
      pwB = mk4(pk_bf16(pw[r0], pw[r0 + 16]), pk_bf16(pw[r0 + 32], pw[r0 + 48]));
      pxB = mk4(pk_bf16(px[r0], px[r0 + 16]), pk_bf16(px[r0 + 32], px[r0 + 48]));
    }
    const float p0w0 = pw[4 * g + 0], p0w1 = pw[4 * g + 1],
                p0w2 = pw[4 * g + 2], p0w3 = pw[4 * g + 3];
    const float px0 = px[x];

    float acc  = 0.f;
    float msum = 0.f;
    v4f al = {0.f, 0.f, 0.f, 0.f};
    const v4f z4 = {0.f, 0.f, 0.f, 0.f};

    __syncthreads();                       // wait buf0
#pragma unroll 1
    for (int ch = 0; ch < nch; ++ch) {
      const int tb  = ch * CH;
      const int buf = ch & 1;
      const int te  = (len < tb + CH) ? len : (tb + CH);
      const u2* Eb  = Elds[buf];

      float Mrow = Mbufs[buf][l & 31];     // lane l<32 holds M[tb+l]
      if (l < 32 && tb + l < len) msum += Mrow;

      int t = tb;
      u2 Ec = Eb[eidx(0, x, g)];

#define SCAN_STEP(TCUR, PF)                                                 \
      {                                                                     \
        u2 En_ = Ec;                                                        \
        PF                                                                  \
        const float Ms_ = rdlane(Mrow, (TCUR) & 31);                        \
        const float e0 = fexp2(bf_lo(Ec.x) - Ms_);                          \
        const float e1 = fexp2(bf_hi(Ec.x) - Ms_);                          \
        const float e2 = fexp2(bf_lo(Ec.y) - Ms_);                          \
        const float e3 = fexp2(bf_hi(Ec.y) - Ms_);                          \
        v4s a16 = mk4(pktrunc(al[0], al[1]), pktrunc(al[2], al[3]));        \
        v4f d1 = mfma16(a16, pwB, z4);                                      \
        v4s d16 = mk4(pktrunc(d1[0], d1[1]), pktrunc(d1[2], d1[3]));        \
        v4f d2 = mfma16(d16, pxB, z4);                                      \
        al[0] = d2[0] * e0; al[1] = d2[1] * e1;                             \
        al[2] = d2[2] * e2; al[3] = d2[3] * e3;                             \
        Ec = En_;                                                           \
      }

#define RENORM                                                              \
      {                                                                     \
        float S = (al[0] + al[1]) + (al[2] + al[3]);                        \
        _Pragma("unroll")                                                   \
        for (int o = 1; o <= 32; o <<= 1) S += __shfl_xor(S, o, 64);        \
        S = fmaxf(S, 1e-35f);                                               \
        const float r = __builtin_amdgcn_rcpf(S);                           \
        al[0] *= r; al[1] *= r; al[2] *= r; al[3] *= r;                     \
        acc += __log2f(S);                                                  \
      }

      if (ch == 0) {   // peel t = 0: alpha0 = prior * e
        const float Ms_ = rdlane(Mrow, 0);
        const float e0 = fexp2(bf_lo(Ec.x) - Ms_);
        const float e1 = fexp2(bf_hi(Ec.x) - Ms_);
        const float e2 = fexp2(bf_lo(Ec.y) - Ms_);
        const float e3 = fexp2(bf_hi(Ec.y) - Ms_);
        al[0] = p0w0 * px0 * e0; al[1] = p0w1 * px0 * e1;
        al[2] = p0w2 * px0 * e2; al[3] = p0w3 * px0 * e3;
        t = 1;
        if (t < te) Ec = Eb[eidx(1, x, g)];
      }

      while (t < te && (t & 7)) {     // guarded entry until 8-aligned
        SCAN_STEP(t,
          if (t + 1 < te) { En_ = Eb[eidx((t + 1) & 31, x, g)]; })
        if ((t & 7) == 7) RENORM
        ++t;
      }

      const int ng = (te - t) >> 3;   // fast path: 8-step groups
      if (ng > 0) {
        u2 E1 = Eb[eidx((t + 1) & 31, x, g)];
        float snap = 0.f, Sready = 1.0f, rdy = 1.0f;
#pragma unroll 1
        for (int gi = 0; gi < ng; ++gi) {
#pragma unroll
          for (int k = 0; k < 8; ++k) {
            u2 E2 = Eb[eidx((t + k + 2) & 31, x, g)];   // 2-deep prefetch
            const float Ms_ = rdlane(Mrow, (t + k) & 31);
            float e0 = fexp2(bf_lo(Ec.x) - Ms_);
            float e1 = fexp2(bf_hi(Ec.x) - Ms_);
            float e2 = fexp2(bf_lo(Ec.y) - Ms_);
            float e3 = fexp2(bf_hi(Ec.y) - Ms_);
            if (k == 0) {       // apply previous group's renorm (off chain)
              e0 *= rdy; e1 *= rdy; e2 *= rdy; e3 *= rdy;
              acc += __log2f(Sready);
            }
            v4s a16 = mk4(pktrunc(al[0], al[1]), pktrunc(al[2], al[3]));
            v4f d1 = mfma16(a16, pwB, z4);
            v4s d16 = mk4(pktrunc(d1[0], d1[1]), pktrunc(d1[2], d1[3]));
            v4f d2 = mfma16(d16, pxB, z4);
            al[0] = d2[0] * e0; al[1] = d2[1] * e1;
            al[2] = d2[2] * e2; al[3] = d2[3] * e3;
            if (k == 0) snap = (al[0] + al[1]) + (al[2] + al[3]);
            if (k >= 1 && k <= 6)
              snap += __shfl_xor(snap, 1 << (k - 1), 64);
            if (k == 7) {
              Sready = fmaxf(snap, 1e-35f);
              rdy = __builtin_amdgcn_rcpf(Sready);
            }
            Ec = E1; E1 = E2;
          }
          t += 8;
        }
        acc += __log2f(Sready);     // flush pending renorm
        al[0] *= rdy; al[1] *= rdy; al[2] *= rdy; al[3] *= rdy;
      }

      while (t < te) {                // guarded tail
        SCAN_STEP(t,
          if (t + 1 < te) { En_ = Eb[eidx((t + 1) & 31, x, g)]; })
        if ((t & 7) == 7) RENORM
        ++t;
      }
#undef SCAN_STEP
#undef RENORM

      __syncthreads();   // scan(ch) done; producer's GEMM(ch+1) done
    }

    // ---------- finalize ----------
    float S = (al[0] + al[1]) + (al[2] + al[3]);
#pragma unroll
    for (int o = 1; o <= 32; o <<= 1) S += __shfl_xor(S, o, 64);
    S = fmaxf(S, 1e-35f);
    acc += __log2f(S);

#pragma unroll
    for (int o = 1; o <= 32; o <<= 1) msum += __shfl_xor(msum, o, 64);

    if (l == 0) out[b] = LN2 * (acc + msum);
  }
}

} // namespace

extern "C" void kernel_launch(void* const* d_in, const int* in_sizes, int n_in,
                              void* d_out, int out_size, void* d_ws, size_t ws_size,
                              hipStream_t stream) {
  const float* seq     = (const float*)d_in[0];
  const int*   lengths = (const int*)d_in[1];
  const float* pw      = (const float*)d_in[2];
  const float* px      = (const float*)d_in[3];
  const float* py      = (const float*)d_in[4];
  float*       out     = (float*)d_out;
  u2*          wsdif   = (u2*)d_ws;    // 32 KB shared B-frag table

  hipLaunchKernelGGL(fhmm_fwd, dim3(1024), dim3(128), 0, stream,
                     seq, lengths, pw, px, py, out, wsdif);
}